// Round 15
// baseline (64.065 us; speedup 1.0000x reference)
//
#include <hip/hip_runtime.h>
#include <hip/hip_bf16.h>
#include <math.h>

#define EMB 30
#define NS 64   // D splits (one per block); partials layout [q][NS][20]
#define JT 128  // j's per split (D/NS)
#define SUB 64  // j's per LDS subtile (16 KB)

typedef __attribute__((ext_vector_type(8))) short bf16x8;
typedef __attribute__((ext_vector_type(4))) float f32x4;
typedef __attribute__((ext_vector_type(4))) unsigned u32x4;
typedef __attribute__((ext_vector_type(2))) _Float16 f16x2;

__device__ __forceinline__ float leakyf(float x) { return x > 0.0f ? x : 0.1f * x; }

__device__ __forceinline__ unsigned short f2b(float x) {
  __hip_bfloat16 h = __float2bfloat16(x);
  union { __hip_bfloat16 h; unsigned short u; } cv;
  cv.h = h;
  return cv.u;
}

// true packed f16 min/max — forces v_pk_*_f16
__device__ __forceinline__ unsigned pkmax(unsigned a, unsigned b) {
  unsigned d;
  asm("v_pk_max_f16 %0, %1, %2" : "=v"(d) : "v"(a), "v"(b));
  return d;
}
__device__ __forceinline__ unsigned pkmin(unsigned a, unsigned b) {
  unsigned d;
  asm("v_pk_min_f16 %0, %1, %2" : "=v"(d) : "v"(a), "v"(b));
  return d;
}
__device__ __forceinline__ unsigned cvtpku(float a, float b) {
  return __builtin_bit_cast(unsigned, __builtin_amdgcn_cvt_pkrtz(a, b));
}

// packed insert into descending-sorted t[5] — med3 identity, depth 2
__device__ __forceinline__ void ins5h(unsigned (&t)[5], unsigned v) {
  unsigned n0 = pkmax(t[0], v);
  unsigned n1 = pkmax(pkmin(t[0], v), t[1]);
  unsigned n2 = pkmax(pkmin(t[1], v), t[2]);
  unsigned n3 = pkmax(pkmin(t[2], v), t[3]);
  unsigned n4 = pkmax(pkmin(t[3], v), t[4]);
  t[0] = n0; t[1] = n1; t[2] = n2; t[3] = n3; t[4] = n4;
}

// packed top-5 of merge(a,b), both sorted descending
__device__ __forceinline__ void merge5h(unsigned (&a)[5], const unsigned (&b)[5]) {
  unsigned c0 = pkmax(a[0], b[0]);
  unsigned c1 = pkmax(pkmax(pkmin(a[0], b[0]), a[1]), b[1]);
  unsigned c2 = pkmax(pkmax(pkmin(a[0], b[1]), pkmin(a[1], b[0])), pkmax(a[2], b[2]));
  unsigned c3 = pkmax(pkmax(pkmin(a[0], b[2]), pkmin(a[1], b[1])),
                      pkmax(pkmin(a[2], b[0]), pkmax(a[3], b[3])));
  unsigned c4 = pkmax(pkmax(pkmax(pkmin(a[0], b[3]), pkmin(a[1], b[2])),
                            pkmax(pkmin(a[2], b[1]), pkmin(a[3], b[0]))),
                      pkmax(a[4], b[4]));
  a[0] = c0; a[1] = c1; a[2] = c2; a[3] = c3; a[4] = c4;
}

// float top-5 merge (pool stage)
__device__ __forceinline__ void merge5(float (&a)[5], const float (&b)[5]) {
  float c0 = fmaxf(a[0], b[0]);
  float c1 = fmaxf(fmaxf(fminf(a[0], b[0]), a[1]), b[1]);
  float c2 = fmaxf(fmaxf(fminf(a[0], b[1]), fminf(a[1], b[0])), fmaxf(a[2], b[2]));
  float c3 = fmaxf(fmaxf(fminf(a[0], b[2]), fminf(a[1], b[1])),
                   fmaxf(fminf(a[2], b[0]), fmaxf(a[3], b[3])));
  float c4 = fmaxf(fmaxf(fmaxf(fminf(a[0], b[3]), fminf(a[1], b[2])),
                         fmaxf(fminf(a[2], b[1]), fminf(a[3], b[0]))),
                   fmaxf(a[4], b[4]));
  a[0] = c0; a[1] = c1; a[2] = c2; a[3] = c3; a[4] = c4;
}

// Parallel prep: block = 64 rows x 4 threads/row (unchanged from r14).
__global__ __launch_bounds__(256) void prep_all_kernel(
    const float* __restrict__ Xq, const float* __restrict__ X1,
    const float* __restrict__ X2, int Q, int D,
    const float* __restrict__ Wc, const float* __restrict__ bc,
    const float* __restrict__ qidf, const float* __restrict__ Wqw,
    unsigned short* __restrict__ qr, unsigned short* __restrict__ qc,
    unsigned short* __restrict__ cmb, float* __restrict__ logits) {
  __shared__ float sX[66 * EMB];        // rows l0-1 .. l0+64
  __shared__ float sW[EMB * EMB * 3];
  __shared__ float sB[EMB];
  __shared__ float sQw[EMB + 1];
  int tid = threadIdx.x;
  int nbQ = Q >> 6, nbD = D >> 6;
  int b = blockIdx.x;
  const float* X;
  int L, l0, slot = 0;
  bool isQ = false;
  if (b < nbQ) { X = Xq; L = Q; l0 = b << 6; isQ = true; }
  else if (b < nbQ + nbD) { X = X1; L = D; l0 = (b - nbQ) << 6; slot = 0; }
  else { X = X2; L = D; l0 = (b - nbQ - nbD) << 6; slot = 2; }

  for (int idx = tid; idx < EMB * EMB * 3; idx += 256) sW[idx] = Wc[idx];
  if (tid < EMB) sB[tid] = bc[tid];
  if (tid < EMB + 1) sQw[tid] = Wqw[tid];
  int base = l0 * EMB - EMB;
  int lim = L * EMB;
  for (int idx = tid; idx < 66 * EMB; idx += 256) {
    int g = base + idx;
    sX[idx] = (g >= 0 && g < lim) ? X[g] : 0.0f;
  }
  __syncthreads();

  int r = tid >> 2, sub = tid & 3;      // 64 rows x 4 subs
  int l = l0 + r;
  int o0 = sub * 8;                     // output range [o0, o0+8) ∩ [0,30)
  const float* xmP = sX + r * EMB;
  const float* x0P = sX + (r + 1) * EMB;
  const float* xpP = sX + (r + 2) * EMB;
  const float* wP  = sW + o0 * 90;

  float acc[8];
#pragma unroll
  for (int oo = 0; oo < 8; ++oo)
    acc[oo] = (o0 + oo < EMB) ? sB[o0 + oo] : 0.0f;
  float sr = 0.0f;
  for (int i = 0; i < EMB; ++i) {
    float xm = xmP[i], x0v = x0P[i], xp = xpP[i];
    sr += x0v * x0v;
#pragma unroll
    for (int oo = 0; oo < 8; ++oo) {
      if (o0 + oo < EMB) {
        acc[oo] += wP[oo * 90 + i * 3 + 0] * xm;
        acc[oo] += wP[oo * 90 + i * 3 + 1] * x0v;
        acc[oo] += wP[oo * 90 + i * 3 + 2] * xp;
      }
    }
  }
  float y[8];
  float sc = 0.0f, lg = 0.0f;
#pragma unroll
  for (int oo = 0; oo < 8; ++oo) {
    if (o0 + oo < EMB) {
      float v = leakyf(acc[oo]) + x0P[o0 + oo];
      y[oo] = v;
      sc += v * v;
      lg += v * sQw[o0 + oo];
    } else y[oo] = 0.0f;
  }
  sc += __shfl_xor(sc, 1); sc += __shfl_xor(sc, 2);
  lg += __shfl_xor(lg, 1); lg += __shfl_xor(lg, 2);
  float rnr = 1.0f / sqrtf(sr);
  float rnc = 1.0f / sqrtf(sc);
  if (isQ && sub == 0) logits[l] = lg + qidf[l] * sQw[EMB];

  unsigned rd[4], cd[4];
#pragma unroll
  for (int kk = 0; kk < 4; ++kk) {
    int k = sub * 4 + kk;
    if (k < 15) {
      rd[kk] = (unsigned)f2b(x0P[2 * k] * rnr) | ((unsigned)f2b(x0P[2 * k + 1] * rnr) << 16);
      int oo = 2 * k - o0;
      cd[kk] = (unsigned)f2b(y[oo] * rnc) | ((unsigned)f2b(y[oo + 1] * rnc) << 16);
    } else { rd[kk] = 0u; cd[kk] = 0u; }
  }
  if (isQ) {
    unsigned* rw = (unsigned*)(qr + (size_t)l * 32);
    unsigned* cw = (unsigned*)(qc + (size_t)l * 32);
#pragma unroll
    for (int kk = 0; kk < 4; ++kk) { rw[sub * 4 + kk] = rd[kk]; cw[sub * 4 + kk] = cd[kk]; }
  } else {
    unsigned* rowp = (unsigned*)(cmb + (size_t)l * 128);
    int sx = (l & 7) << 2;
#pragma unroll
    for (int kk = 0; kk < 4; ++kk) {
      int k = sub * 4 + kk;
      rowp[(slot * 16 + k) ^ sx]       = rd[kk];
      rowp[((slot + 1) * 16 + k) ^ sx] = cd[kk];
    }
  }
}

// Block = 4 waves × 1 D-split; each wave owns 32 q's (2 q-subtiles).
// SWAPPED MFMA operands. This round: stage-loads issued before q-fragment
// loads; inner loop reordered LOADX(next) -> CONSUME(cur) -> MFMA8(next)
// with double-buffered X regs; vectorized partials stores.
__global__ __launch_bounds__(256, 4) void main_kernel(
    const unsigned short* __restrict__ qrA, const unsigned short* __restrict__ qcA,
    const unsigned* __restrict__ cmb32,
    float* __restrict__ partials, int Q, int D) {
  __shared__ __align__(16) unsigned lds[2][SUB * 64];   // 2 x 16 KB
  int tid = threadIdx.x;
  int wave = tid >> 6, lane = tid & 63;
  int lo = lane & 15, hi = lane >> 4;
  int qt = blockIdx.x >> 6, ds = blockIdx.x & (NS - 1);
  int qb0 = qt * 128 + wave * 32;      // wave covers q rows qb0..qb0+31

  // stage-0 loads FIRST (critical path: global -> LDS write -> barrier)
  const u32x4* gsrc = (const u32x4*)(cmb32 + (size_t)ds * JT * 64);
  u32x4 R[4];
#pragma unroll
  for (int i = 0; i < 4; ++i) R[i] = gsrc[i * 256 + tid];

  // q fragments overlap the staging latency
  bf16x8 aR0 = *(const bf16x8*)(qrA + (size_t)(qb0 + lo) * 32 + hi * 8);
  bf16x8 aC0 = *(const bf16x8*)(qcA + (size_t)(qb0 + lo) * 32 + hi * 8);
  bf16x8 aR1 = *(const bf16x8*)(qrA + (size_t)(qb0 + 16 + lo) * 32 + hi * 8);
  bf16x8 aC1 = *(const bf16x8*)(qcA + (size_t)(qb0 + 16 + lo) * 32 + hi * 8);

  unsigned t[4][5];   // [0]=q0 raw(d1,d2) [1]=q0 conv [2]=q1 raw [3]=q1 conv
#pragma unroll
  for (int li = 0; li < 4; ++li)
#pragma unroll
    for (int k = 0; k < 5; ++k) t[li][k] = 0xC000C000u;  // packed f16 -2.0

#pragma unroll
  for (int i = 0; i < 4; ++i) ((u32x4*)lds[0])[i * 256 + tid] = R[i];

  int swzA = ((lo & 7) << 2);
  int c0 = (0  + hi * 4) ^ swzA;
  int c1 = (16 + hi * 4) ^ swzA;
  int c2 = (32 + hi * 4) ^ swzA;
  int c3 = (48 + hi * 4) ^ swzA;

  f32x4 s0a, s1a, s2a, s3a, s0b, s1b, s2b, s3b;

#define LOADX(IT, X0, X1, X2, X3) {                                            \
    const unsigned* rp = L + ((IT) * 16 + lo) * 64;                            \
    X0 = *(const bf16x8*)(rp + c0); X1 = *(const bf16x8*)(rp + c1);            \
    X2 = *(const bf16x8*)(rp + c2); X3 = *(const bf16x8*)(rp + c3); }

#define MFMA8(X0, X1, X2, X3) {                                                \
    f32x4 z = {0.0f, 0.0f, 0.0f, 0.0f};                                        \
    s0a = __builtin_amdgcn_mfma_f32_16x16x32_bf16(X0, aR0, z, 0, 0, 0);        \
    s1a = __builtin_amdgcn_mfma_f32_16x16x32_bf16(X1, aC0, z, 0, 0, 0);        \
    s2a = __builtin_amdgcn_mfma_f32_16x16x32_bf16(X2, aR0, z, 0, 0, 0);        \
    s3a = __builtin_amdgcn_mfma_f32_16x16x32_bf16(X3, aC0, z, 0, 0, 0);        \
    s0b = __builtin_amdgcn_mfma_f32_16x16x32_bf16(X0, aR1, z, 0, 0, 0);        \
    s1b = __builtin_amdgcn_mfma_f32_16x16x32_bf16(X1, aC1, z, 0, 0, 0);        \
    s2b = __builtin_amdgcn_mfma_f32_16x16x32_bf16(X2, aR1, z, 0, 0, 0);        \
    s3b = __builtin_amdgcn_mfma_f32_16x16x32_bf16(X3, aC1, z, 0, 0, 0); }

#define CONSUME() _Pragma("unroll") for (int r = 0; r < 4; ++r) {              \
    ins5h(t[0], cvtpku(s0a[r], s2a[r]));                                       \
    ins5h(t[1], cvtpku(s1a[r], s3a[r]));                                       \
    ins5h(t[2], cvtpku(s0b[r], s2b[r]));                                       \
    ins5h(t[3], cvtpku(s1b[r], s3b[r])); }

#pragma unroll 1
  for (int st = 0; st < 2; ++st) {
    __syncthreads();                   // lds[st] ready for all waves
    if (st == 0) {                     // issue next subtile's loads early (T14)
#pragma unroll
      for (int i = 0; i < 4; ++i) R[i] = gsrc[1024 + i * 256 + tid];
    }
    const unsigned* L = lds[st];
    bf16x8 Xa0, Xa1, Xa2, Xa3, Xb0, Xb1, Xb2, Xb3;
    LOADX(0, Xa0, Xa1, Xa2, Xa3)
    MFMA8(Xa0, Xa1, Xa2, Xa3)
    LOADX(1, Xb0, Xb1, Xb2, Xb3)      // ds_reads hide under CONSUME's VALU
    CONSUME()
    MFMA8(Xb0, Xb1, Xb2, Xb3)
    LOADX(2, Xa0, Xa1, Xa2, Xa3)
    CONSUME()
    MFMA8(Xa0, Xa1, Xa2, Xa3)
    LOADX(3, Xb0, Xb1, Xb2, Xb3)
    CONSUME()
    MFMA8(Xb0, Xb1, Xb2, Xb3)
    CONSUME()
    __syncthreads();                   // all waves done reading lds[st]
    if (st == 0) {
#pragma unroll
      for (int i = 0; i < 4; ++i) ((u32x4*)lds[1])[i * 256 + tid] = R[i];
    }
  }
#undef LOADX
#undef MFMA8
#undef CONSUME

  // merge across the 4 hi-groups (same q): xor16 (ds_swizzle) + xor32 (shfl)
#pragma unroll
  for (int li = 0; li < 4; ++li) {
    unsigned b[5];
#pragma unroll
    for (int k = 0; k < 5; ++k)
      b[k] = (unsigned)__builtin_amdgcn_ds_swizzle((int)t[li][k], 0x401F);
    merge5h(t[li], b);
  }
#pragma unroll
  for (int li = 0; li < 4; ++li) {
    unsigned b[5];
#pragma unroll
    for (int k = 0; k < 5; ++k) b[k] = (unsigned)__shfl_xor((int)t[li][k], 32);
    merge5h(t[li], b);
  }

  if (lane < 16) {
#pragma unroll
    for (int qs = 0; qs < 2; ++qs) {
      int q = qb0 + qs * 16 + lo;
      float* dst = partials + ((size_t)q * NS + ds) * 20;
      float a[20];
#pragma unroll
      for (int k = 0; k < 5; ++k) {
        f16x2 t0 = __builtin_bit_cast(f16x2, t[qs * 2 + 0][k]);
        f16x2 t1 = __builtin_bit_cast(f16x2, t[qs * 2 + 1][k]);
        a[k]      = (float)t0[0];      // d1 raw
        a[5 + k]  = (float)t1[0];      // d1 conv
        a[10 + k] = (float)t0[1];      // d2 raw
        a[15 + k] = (float)t1[1];      // d2 conv
      }
#pragma unroll
      for (int v = 0; v < 5; ++v)
        ((f32x4*)dst)[v] = *(f32x4*)(a + v * 4);
    }
  }
}

// Pool + final fused: block = 4 q's (one per wave); lane loads split `lane`
// directly from global; 6-round shfl tree; MLP on lane 0 of each wave;
// last block (atomic counter) reduces blockSums and emits the outputs.
__global__ __launch_bounds__(256) void pool_kernel(
    const float* __restrict__ logits, const float* __restrict__ partials,
    const float* __restrict__ W1, const float* __restrict__ W2,
    const float* __restrict__ gaf, const float* __restrict__ baf,
    const float* __restrict__ Wout, float* __restrict__ blockSums,
    int* __restrict__ counter, float* __restrict__ out, int Q) {
  __shared__ float sred[4];
  __shared__ float r1[4], r2[4];
  __shared__ int isLast;
  int tid = threadIdx.x;
  int lane = tid & 63, wave = tid >> 6;

  float lmax = -3.0e38f;
  for (int q = tid; q < Q; q += 256) lmax = fmaxf(lmax, logits[q]);
#pragma unroll
  for (int m = 1; m < 64; m <<= 1) lmax = fmaxf(lmax, __shfl_xor(lmax, m));
  if (lane == 0) sred[wave] = lmax;
  __syncthreads();
  float M = fmaxf(fmaxf(sred[0], sred[1]), fmaxf(sred[2], sred[3]));
  __syncthreads();
  float lsum = 0.0f;
  for (int q = tid; q < Q; q += 256) lsum += expf(logits[q] - M);
#pragma unroll
  for (int m = 1; m < 64; m <<= 1) lsum += __shfl_xor(lsum, m);
  if (lane == 0) sred[wave] = lsum;
  __syncthreads();
  float rS = 1.0f / (sred[0] + sred[1] + sred[2] + sred[3]);

  int qglob = blockIdx.x * 4 + wave;
  const float* p0 = partials + ((size_t)qglob * NS + lane) * 20;
  float T[4][5];
#pragma unroll
  for (int li = 0; li < 4; ++li)
#pragma unroll
    for (int k = 0; k < 5; ++k) T[li][k] = p0[li * 5 + k];
#pragma unroll
  for (int m = 32; m >= 1; m >>= 1) {
#pragma unroll
    for (int li = 0; li < 4; ++li) {
      float b[5];
#pragma unroll
      for (int k = 0; k < 5; ++k) b[k] = __shfl_xor(T[li][k], m);
      merge5(T[li], b);
    }
  }
  if (lane == 0) {
    float w = expf(logits[qglob] - M) * rS;
    float s1 = 0.0f, s2 = 0.0f;
#pragma unroll
    for (int d = 0; d < 2; ++d) {
      const float (&Ti)[5] = T[d ? 2 : 0];   // raw
      const float (&Ts)[5] = T[d ? 3 : 1];   // conv
      float c = 0.0f;
#pragma unroll
      for (int k = 0; k < 5; ++k) c += (Ti[k] > 0.999f) ? 1.0f : 0.0f;  // min(cnt,5)
      float tmp[6];
      tmp[0] = (Ti[0] > 0.999f) ? 1.0f : 0.0f;
      tmp[1] = c * 0.2f;
      tmp[2] = Ti[0];
      tmp[3] = (Ti[0] + Ti[1] + Ti[2] + Ti[3] + Ti[4]) * 0.2f;
      tmp[4] = Ts[0];
      tmp[5] = (Ts[0] + Ts[1] + Ts[2] + Ts[3] + Ts[4]) * 0.2f;
      float lov = 0.0f;
#pragma unroll
      for (int r = 0; r < 8; ++r) {
        float h = 0.0f;
#pragma unroll
        for (int cidx = 0; cidx < 6; ++cidx) h += W1[r * 6 + cidx] * tmp[cidx];
        lov += W2[r] * leakyf(h);
      }
      if (d == 0) s1 = lov * w; else s2 = lov * w;
    }
    r1[wave] = s1; r2[wave] = s2;
  }
  __syncthreads();
  if (tid == 0) {
    blockSums[blockIdx.x * 2]     = r1[0] + r1[1] + r1[2] + r1[3];
    blockSums[blockIdx.x * 2 + 1] = r2[0] + r2[1] + r2[2] + r2[3];
    __threadfence();
    isLast = (atomicAdd(counter, 1) == (int)gridDim.x - 1) ? 1 : 0;
  }
  __syncthreads();
  if (isLast) {
    float s1 = 0.0f, s2 = 0.0f;
    for (int b = tid; b < (int)gridDim.x; b += 256) {
      s1 += blockSums[b * 2];
      s2 += blockSums[b * 2 + 1];
    }
#pragma unroll
    for (int m = 1; m < 64; m <<= 1) { s1 += __shfl_xor(s1, m); s2 += __shfl_xor(s2, m); }
    if (lane == 0) { sred[wave] = s1; r1[wave] = s2; }
    __syncthreads();
    if (tid == 0) {
      float S1 = sred[0] + sred[1] + sred[2] + sred[3];
      float S2 = r1[0] + r1[1] + r1[2] + r1[3];
      float e1 = S1 / (float)Q, e2 = S2 / (float)Q;
      float good = gaf[0] * Wout[0] + gaf[1] * Wout[1] + gaf[2] * Wout[2] + gaf[3] * Wout[3] + e1 * Wout[4];
      float bad  = baf[0] * Wout[0] + baf[1] * Wout[1] + baf[2] * Wout[2] + baf[3] * Wout[3] + e2 * Wout[4];
      float loss = fmaxf(0.0f, 1.0f + bad - good);
      out[0] = loss; out[1] = good; out[2] = bad;
    }
  }
}

extern "C" void kernel_launch(void* const* d_in, const int* in_sizes, int n_in,
                              void* d_out, int out_size, void* d_ws, size_t ws_size,
                              hipStream_t stream) {
  const float* d1   = (const float*)d_in[0];
  const float* d2   = (const float*)d_in[1];
  const float* qe   = (const float*)d_in[2];
  const float* qidf = (const float*)d_in[3];
  const float* gaf  = (const float*)d_in[4];
  const float* baf  = (const float*)d_in[5];
  const float* Wc   = (const float*)d_in[6];
  const float* bc   = (const float*)d_in[7];
  const float* Wqw  = (const float*)d_in[8];
  const float* Wq1  = (const float*)d_in[9];
  const float* Wq2  = (const float*)d_in[10];
  const float* Wout = (const float*)d_in[11];
  int D = in_sizes[0] / EMB;
  int Q = in_sizes[2] / EMB;

  unsigned short* us = (unsigned short*)d_ws;
  unsigned short* cmb = us; us += (size_t)D * 128;
  unsigned short* qrA = us; us += (size_t)Q * 32;
  unsigned short* qcA = us; us += (size_t)Q * 32;
  float* fp = (float*)us;
  float* logits    = fp; fp += Q;
  float* partials  = fp; fp += (size_t)Q * NS * 20;
  float* blockSums = fp; fp += (Q / 4) * 2;
  int* counter     = (int*)fp; fp += 1;

  hipMemsetAsync(counter, 0, sizeof(int), stream);

  int grid = (Q >> 6) + 2 * (D >> 6);
  prep_all_kernel<<<grid, 256, 0, stream>>>(qe, d1, d2, Q, D, Wc, bc, qidf, Wqw,
                                            qrA, qcA, cmb, logits);
  main_kernel<<<(Q / 128) * NS, 256, 0, stream>>>(qrA, qcA, (const unsigned*)cmb,
                                                  partials, Q, D);
  pool_kernel<<<Q / 4, 256, 0, stream>>>(logits, partials, Wq1, Wq2,
                                         gaf, baf, Wout, blockSums, counter,
                                         (float*)d_out, Q);
}

// Round 16
// 55.023 us; speedup vs baseline: 1.1643x; 1.1643x over previous
//
#include <hip/hip_runtime.h>
#include <hip/hip_bf16.h>
#include <math.h>

#define EMB 30
#define NS 64   // D splits (one per block); partials layout [q][NS][20]
#define JT 128  // j's per split (D/NS)
#define SUB 64  // j's per LDS subtile (16 KB)

typedef __attribute__((ext_vector_type(8))) short bf16x8;
typedef __attribute__((ext_vector_type(4))) float f32x4;
typedef __attribute__((ext_vector_type(4))) unsigned u32x4;
typedef __attribute__((ext_vector_type(2))) _Float16 f16x2;

__device__ __forceinline__ float leakyf(float x) { return x > 0.0f ? x : 0.1f * x; }

__device__ __forceinline__ unsigned short f2b(float x) {
  __hip_bfloat16 h = __float2bfloat16(x);
  union { __hip_bfloat16 h; unsigned short u; } cv;
  cv.h = h;
  return cv.u;
}

// true packed f16 min/max — forces v_pk_*_f16
__device__ __forceinline__ unsigned pkmax(unsigned a, unsigned b) {
  unsigned d;
  asm("v_pk_max_f16 %0, %1, %2" : "=v"(d) : "v"(a), "v"(b));
  return d;
}
__device__ __forceinline__ unsigned pkmin(unsigned a, unsigned b) {
  unsigned d;
  asm("v_pk_min_f16 %0, %1, %2" : "=v"(d) : "v"(a), "v"(b));
  return d;
}
__device__ __forceinline__ unsigned cvtpku(float a, float b) {
  return __builtin_bit_cast(unsigned, __builtin_amdgcn_cvt_pkrtz(a, b));
}

// packed insert into descending-sorted t[5] — med3 identity, depth 2:
// t0' = max(t0,v); ti' = max(min(t_{i-1}, v), t_i)   (all read OLD state)
__device__ __forceinline__ void ins5h(unsigned (&t)[5], unsigned v) {
  unsigned n0 = pkmax(t[0], v);
  unsigned n1 = pkmax(pkmin(t[0], v), t[1]);
  unsigned n2 = pkmax(pkmin(t[1], v), t[2]);
  unsigned n3 = pkmax(pkmin(t[2], v), t[3]);
  unsigned n4 = pkmax(pkmin(t[3], v), t[4]);
  t[0] = n0; t[1] = n1; t[2] = n2; t[3] = n3; t[4] = n4;
}

// packed top-5 of merge(a,b), both sorted descending
__device__ __forceinline__ void merge5h(unsigned (&a)[5], const unsigned (&b)[5]) {
  unsigned c0 = pkmax(a[0], b[0]);
  unsigned c1 = pkmax(pkmax(pkmin(a[0], b[0]), a[1]), b[1]);
  unsigned c2 = pkmax(pkmax(pkmin(a[0], b[1]), pkmin(a[1], b[0])), pkmax(a[2], b[2]));
  unsigned c3 = pkmax(pkmax(pkmin(a[0], b[2]), pkmin(a[1], b[1])),
                      pkmax(pkmin(a[2], b[0]), pkmax(a[3], b[3])));
  unsigned c4 = pkmax(pkmax(pkmax(pkmin(a[0], b[3]), pkmin(a[1], b[2])),
                            pkmax(pkmin(a[2], b[1]), pkmin(a[3], b[0]))),
                      pkmax(a[4], b[4]));
  a[0] = c0; a[1] = c1; a[2] = c2; a[3] = c3; a[4] = c4;
}

// float top-5 merge (pool stage)
__device__ __forceinline__ void merge5(float (&a)[5], const float (&b)[5]) {
  float c0 = fmaxf(a[0], b[0]);
  float c1 = fmaxf(fmaxf(fminf(a[0], b[0]), a[1]), b[1]);
  float c2 = fmaxf(fmaxf(fminf(a[0], b[1]), fminf(a[1], b[0])), fmaxf(a[2], b[2]));
  float c3 = fmaxf(fmaxf(fminf(a[0], b[2]), fminf(a[1], b[1])),
                   fmaxf(fminf(a[2], b[0]), fmaxf(a[3], b[3])));
  float c4 = fmaxf(fmaxf(fmaxf(fminf(a[0], b[3]), fminf(a[1], b[2])),
                         fmaxf(fminf(a[2], b[1]), fminf(a[3], b[0]))),
                   fmaxf(a[4], b[4]));
  a[0] = c0; a[1] = c1; a[2] = c2; a[3] = c3; a[4] = c4;
}

// Parallel prep: block = 64 rows x 4 threads/row. W staged in LDS (broadcast
// reads); per-thread 8 of 30 conv outputs in registers; norms/logit via
// 4-lane quad shfl reduce. Outputs: questions -> qr/qc [L][32] bf16 + logits;
// docs -> cmb[j] 256B rows (slots d1r,d1c,d2r,d2c × 32B), dwords XOR-swizzled
// by (j&7)<<2 so main_kernel's LDS image is bank-conflict-reduced.
__global__ __launch_bounds__(256) void prep_all_kernel(
    const float* __restrict__ Xq, const float* __restrict__ X1,
    const float* __restrict__ X2, int Q, int D,
    const float* __restrict__ Wc, const float* __restrict__ bc,
    const float* __restrict__ qidf, const float* __restrict__ Wqw,
    unsigned short* __restrict__ qr, unsigned short* __restrict__ qc,
    unsigned short* __restrict__ cmb, float* __restrict__ logits) {
  __shared__ float sX[66 * EMB];        // rows l0-1 .. l0+64
  __shared__ float sW[EMB * EMB * 3];
  __shared__ float sB[EMB];
  __shared__ float sQw[EMB + 1];
  int tid = threadIdx.x;
  int nbQ = Q >> 6, nbD = D >> 6;
  int b = blockIdx.x;
  const float* X;
  int L, l0, slot = 0;
  bool isQ = false;
  if (b < nbQ) { X = Xq; L = Q; l0 = b << 6; isQ = true; }
  else if (b < nbQ + nbD) { X = X1; L = D; l0 = (b - nbQ) << 6; slot = 0; }
  else { X = X2; L = D; l0 = (b - nbQ - nbD) << 6; slot = 2; }

  for (int idx = tid; idx < EMB * EMB * 3; idx += 256) sW[idx] = Wc[idx];
  if (tid < EMB) sB[tid] = bc[tid];
  if (tid < EMB + 1) sQw[tid] = Wqw[tid];
  int base = l0 * EMB - EMB;
  int lim = L * EMB;
  for (int idx = tid; idx < 66 * EMB; idx += 256) {
    int g = base + idx;
    sX[idx] = (g >= 0 && g < lim) ? X[g] : 0.0f;
  }
  __syncthreads();

  int r = tid >> 2, sub = tid & 3;      // 64 rows x 4 subs
  int l = l0 + r;
  int o0 = sub * 8;                     // output range [o0, o0+8) ∩ [0,30)
  const float* xmP = sX + r * EMB;
  const float* x0P = sX + (r + 1) * EMB;
  const float* xpP = sX + (r + 2) * EMB;
  const float* wP  = sW + o0 * 90;

  float acc[8];
#pragma unroll
  for (int oo = 0; oo < 8; ++oo)
    acc[oo] = (o0 + oo < EMB) ? sB[o0 + oo] : 0.0f;
  float sr = 0.0f;
  for (int i = 0; i < EMB; ++i) {
    float xm = xmP[i], x0v = x0P[i], xp = xpP[i];
    sr += x0v * x0v;
#pragma unroll
    for (int oo = 0; oo < 8; ++oo) {
      if (o0 + oo < EMB) {
        acc[oo] += wP[oo * 90 + i * 3 + 0] * xm;
        acc[oo] += wP[oo * 90 + i * 3 + 1] * x0v;
        acc[oo] += wP[oo * 90 + i * 3 + 2] * xp;
      }
    }
  }
  float y[8];
  float sc = 0.0f, lg = 0.0f;
#pragma unroll
  for (int oo = 0; oo < 8; ++oo) {
    if (o0 + oo < EMB) {
      float v = leakyf(acc[oo]) + x0P[o0 + oo];
      y[oo] = v;
      sc += v * v;
      lg += v * sQw[o0 + oo];
    } else y[oo] = 0.0f;
  }
  sc += __shfl_xor(sc, 1); sc += __shfl_xor(sc, 2);
  lg += __shfl_xor(lg, 1); lg += __shfl_xor(lg, 2);
  float rnr = 1.0f / sqrtf(sr);
  float rnc = 1.0f / sqrtf(sc);
  if (isQ && sub == 0) logits[l] = lg + qidf[l] * sQw[EMB];

  unsigned rd[4], cd[4];
#pragma unroll
  for (int kk = 0; kk < 4; ++kk) {
    int k = sub * 4 + kk;
    if (k < 15) {
      rd[kk] = (unsigned)f2b(x0P[2 * k] * rnr) | ((unsigned)f2b(x0P[2 * k + 1] * rnr) << 16);
      int oo = 2 * k - o0;
      cd[kk] = (unsigned)f2b(y[oo] * rnc) | ((unsigned)f2b(y[oo + 1] * rnc) << 16);
    } else { rd[kk] = 0u; cd[kk] = 0u; }
  }
  if (isQ) {
    unsigned* rw = (unsigned*)(qr + (size_t)l * 32);
    unsigned* cw = (unsigned*)(qc + (size_t)l * 32);
#pragma unroll
    for (int kk = 0; kk < 4; ++kk) { rw[sub * 4 + kk] = rd[kk]; cw[sub * 4 + kk] = cd[kk]; }
  } else {
    unsigned* rowp = (unsigned*)(cmb + (size_t)l * 128);
    int sx = (l & 7) << 2;
#pragma unroll
    for (int kk = 0; kk < 4; ++kk) {
      int k = sub * 4 + kk;
      rowp[(slot * 16 + k) ^ sx]       = rd[kk];
      rowp[((slot + 1) * 16 + k) ^ sx] = cd[kk];
    }
  }
}

// Block = 4 waves × 1 D-split; each wave owns 32 q's (2 q-subtiles resident
// in registers, 8 MFMA per staged doc tile). SWAPPED MFMA operands:
// s = mfma(doc, q) → lane's column = q (lane&15), rows = 4 j's → only
// 2 packed top-5 lists per q-subtile; merge tail is 2 rounds.
__global__ __launch_bounds__(256, 4) void main_kernel(
    const unsigned short* __restrict__ qrA, const unsigned short* __restrict__ qcA,
    const unsigned* __restrict__ cmb32,
    float* __restrict__ partials, int Q, int D) {
  __shared__ __align__(16) unsigned lds[2][SUB * 64];   // 2 x 16 KB
  int tid = threadIdx.x;
  int wave = tid >> 6, lane = tid & 63;
  int lo = lane & 15, hi = lane >> 4;
  int qt = blockIdx.x >> 6, ds = blockIdx.x & (NS - 1);
  int qb0 = qt * 128 + wave * 32;      // wave covers q rows qb0..qb0+31
  bf16x8 aR0 = *(const bf16x8*)(qrA + (size_t)(qb0 + lo) * 32 + hi * 8);
  bf16x8 aC0 = *(const bf16x8*)(qcA + (size_t)(qb0 + lo) * 32 + hi * 8);
  bf16x8 aR1 = *(const bf16x8*)(qrA + (size_t)(qb0 + 16 + lo) * 32 + hi * 8);
  bf16x8 aC1 = *(const bf16x8*)(qcA + (size_t)(qb0 + 16 + lo) * 32 + hi * 8);

  unsigned t[4][5];   // [0]=q0 raw(d1,d2) [1]=q0 conv [2]=q1 raw [3]=q1 conv
#pragma unroll
  for (int li = 0; li < 4; ++li)
#pragma unroll
    for (int k = 0; k < 5; ++k) t[li][k] = 0xC000C000u;  // packed f16 -2.0

  const u32x4* gsrc = (const u32x4*)(cmb32 + (size_t)ds * JT * 64);
  u32x4 R[4];
#pragma unroll
  for (int i = 0; i < 4; ++i) R[i] = gsrc[i * 256 + tid];
#pragma unroll
  for (int i = 0; i < 4; ++i) ((u32x4*)lds[0])[i * 256 + tid] = R[i];

  int swzA = ((lo & 7) << 2);
  int c0 = (0  + hi * 4) ^ swzA;
  int c1 = (16 + hi * 4) ^ swzA;
  int c2 = (32 + hi * 4) ^ swzA;
  int c3 = (48 + hi * 4) ^ swzA;

#pragma unroll 1
  for (int st = 0; st < 2; ++st) {
    __syncthreads();                   // lds[st] ready for all waves
    if (st == 0) {                     // issue next subtile's loads early (T14)
#pragma unroll
      for (int i = 0; i < 4; ++i) R[i] = gsrc[1024 + i * 256 + tid];
    }
    const unsigned* L = lds[st];
#pragma unroll
    for (int it = 0; it < 4; ++it) {
      const unsigned* rp = L + (it * 16 + lo) * 64;
      bf16x8 X0 = *(const bf16x8*)(rp + c0);   // d1 raw rows
      bf16x8 X1 = *(const bf16x8*)(rp + c1);   // d1 conv
      bf16x8 X2 = *(const bf16x8*)(rp + c2);   // d2 raw
      bf16x8 X3 = *(const bf16x8*)(rp + c3);   // d2 conv
      f32x4 z = {0.0f, 0.0f, 0.0f, 0.0f};
      // SWAPPED: A=doc (row=j), B=q (col=q) -> D[j][q]
      f32x4 s0a = __builtin_amdgcn_mfma_f32_16x16x32_bf16(X0, aR0, z, 0, 0, 0);
      f32x4 s1a = __builtin_amdgcn_mfma_f32_16x16x32_bf16(X1, aC0, z, 0, 0, 0);
      f32x4 s2a = __builtin_amdgcn_mfma_f32_16x16x32_bf16(X2, aR0, z, 0, 0, 0);
      f32x4 s3a = __builtin_amdgcn_mfma_f32_16x16x32_bf16(X3, aC0, z, 0, 0, 0);
      f32x4 s0b = __builtin_amdgcn_mfma_f32_16x16x32_bf16(X0, aR1, z, 0, 0, 0);
      f32x4 s1b = __builtin_amdgcn_mfma_f32_16x16x32_bf16(X1, aC1, z, 0, 0, 0);
      f32x4 s2b = __builtin_amdgcn_mfma_f32_16x16x32_bf16(X2, aR1, z, 0, 0, 0);
      f32x4 s3b = __builtin_amdgcn_mfma_f32_16x16x32_bf16(X3, aC1, z, 0, 0, 0);
#pragma unroll
      for (int r = 0; r < 4; ++r) {
        ins5h(t[0], cvtpku(s0a[r], s2a[r]));   // q0 raw: lo=d1, hi=d2
        ins5h(t[1], cvtpku(s1a[r], s3a[r]));   // q0 conv
        ins5h(t[2], cvtpku(s0b[r], s2b[r]));   // q1 raw
        ins5h(t[3], cvtpku(s1b[r], s3b[r]));   // q1 conv
      }
    }
    __syncthreads();                   // all waves done reading lds[st]
    if (st == 0) {
#pragma unroll
      for (int i = 0; i < 4; ++i) ((u32x4*)lds[1])[i * 256 + tid] = R[i];
    }
  }

  // merge across the 4 hi-groups (same q): xor16 (ds_swizzle) + xor32 (shfl)
#pragma unroll
  for (int li = 0; li < 4; ++li) {
    unsigned b[5];
#pragma unroll
    for (int k = 0; k < 5; ++k)
      b[k] = (unsigned)__builtin_amdgcn_ds_swizzle((int)t[li][k], 0x401F);
    merge5h(t[li], b);
  }
#pragma unroll
  for (int li = 0; li < 4; ++li) {
    unsigned b[5];
#pragma unroll
    for (int k = 0; k < 5; ++k) b[k] = (unsigned)__shfl_xor((int)t[li][k], 32);
    merge5h(t[li], b);
  }

  if (lane < 16) {
#pragma unroll
    for (int qs = 0; qs < 2; ++qs) {
      int q = qb0 + qs * 16 + lo;
      float* dst = partials + ((size_t)q * NS + ds) * 20;
#pragma unroll
      for (int k = 0; k < 5; ++k) {
        f16x2 t0 = __builtin_bit_cast(f16x2, t[qs * 2 + 0][k]);
        f16x2 t1 = __builtin_bit_cast(f16x2, t[qs * 2 + 1][k]);
        dst[k]      = (float)t0[0];    // d1 raw
        dst[5 + k]  = (float)t1[0];    // d1 conv
        dst[10 + k] = (float)t0[1];    // d2 raw
        dst[15 + k] = (float)t1[1];    // d2 conv
      }
    }
  }
}

// Parallel pool: block = 4 q's (one per wave); lane loads split `lane`
// DIRECTLY from global (L2-resident, no LDS, no bank conflicts), then
// 6-round shfl tree; MLP on lane 0 of each wave.
__global__ __launch_bounds__(256) void pool_kernel(
    const float* __restrict__ logits, const float* __restrict__ partials,
    const float* __restrict__ W1, const float* __restrict__ W2,
    float* __restrict__ blockSums, int Q) {
  __shared__ float sred[4];
  __shared__ float r1[4], r2[4];
  int tid = threadIdx.x;
  int lane = tid & 63, wave = tid >> 6;

  float lmax = -3.0e38f;
  for (int q = tid; q < Q; q += 256) lmax = fmaxf(lmax, logits[q]);
#pragma unroll
  for (int m = 1; m < 64; m <<= 1) lmax = fmaxf(lmax, __shfl_xor(lmax, m));
  if (lane == 0) sred[wave] = lmax;
  __syncthreads();
  float M = fmaxf(fmaxf(sred[0], sred[1]), fmaxf(sred[2], sred[3]));
  __syncthreads();
  float lsum = 0.0f;
  for (int q = tid; q < Q; q += 256) lsum += expf(logits[q] - M);
#pragma unroll
  for (int m = 1; m < 64; m <<= 1) lsum += __shfl_xor(lsum, m);
  if (lane == 0) sred[wave] = lsum;
  __syncthreads();
  float rS = 1.0f / (sred[0] + sred[1] + sred[2] + sred[3]);

  int qglob = blockIdx.x * 4 + wave;
  const float* p0 = partials + ((size_t)qglob * NS + lane) * 20;
  float T[4][5];
#pragma unroll
  for (int li = 0; li < 4; ++li)
#pragma unroll
    for (int k = 0; k < 5; ++k) T[li][k] = p0[li * 5 + k];
#pragma unroll
  for (int m = 32; m >= 1; m >>= 1) {
#pragma unroll
    for (int li = 0; li < 4; ++li) {
      float b[5];
#pragma unroll
      for (int k = 0; k < 5; ++k) b[k] = __shfl_xor(T[li][k], m);
      merge5(T[li], b);
    }
  }
  if (lane == 0) {
    float w = expf(logits[qglob] - M) * rS;
    float s1 = 0.0f, s2 = 0.0f;
#pragma unroll
    for (int d = 0; d < 2; ++d) {
      const float (&Ti)[5] = T[d ? 2 : 0];   // raw
      const float (&Ts)[5] = T[d ? 3 : 1];   // conv
      float c = 0.0f;
#pragma unroll
      for (int k = 0; k < 5; ++k) c += (Ti[k] > 0.999f) ? 1.0f : 0.0f;  // min(cnt,5)
      float tmp[6];
      tmp[0] = (Ti[0] > 0.999f) ? 1.0f : 0.0f;
      tmp[1] = c * 0.2f;
      tmp[2] = Ti[0];
      tmp[3] = (Ti[0] + Ti[1] + Ti[2] + Ti[3] + Ti[4]) * 0.2f;
      tmp[4] = Ts[0];
      tmp[5] = (Ts[0] + Ts[1] + Ts[2] + Ts[3] + Ts[4]) * 0.2f;
      float lov = 0.0f;
#pragma unroll
      for (int r = 0; r < 8; ++r) {
        float h = 0.0f;
#pragma unroll
        for (int cidx = 0; cidx < 6; ++cidx) h += W1[r * 6 + cidx] * tmp[cidx];
        lov += W2[r] * leakyf(h);
      }
      if (d == 0) s1 = lov * w; else s2 = lov * w;
    }
    r1[wave] = s1; r2[wave] = s2;
  }
  __syncthreads();
  if (tid == 0) {
    blockSums[blockIdx.x * 2]     = r1[0] + r1[1] + r1[2] + r1[3];
    blockSums[blockIdx.x * 2 + 1] = r2[0] + r2[1] + r2[2] + r2[3];
  }
}

__global__ __launch_bounds__(64) void final_kernel(
    const float* __restrict__ blockSums, int nBlocks,
    const float* __restrict__ gaf, const float* __restrict__ baf,
    const float* __restrict__ Wout, float* __restrict__ out, int Q) {
  int tid = threadIdx.x;
  float s1 = 0.0f, s2 = 0.0f;
  for (int b = tid; b < nBlocks; b += 64) {
    s1 += blockSums[b * 2];
    s2 += blockSums[b * 2 + 1];
  }
#pragma unroll
  for (int m = 1; m < 64; m <<= 1) { s1 += __shfl_xor(s1, m); s2 += __shfl_xor(s2, m); }
  if (tid == 0) {
    float e1 = s1 / (float)Q, e2 = s2 / (float)Q;
    float good = gaf[0] * Wout[0] + gaf[1] * Wout[1] + gaf[2] * Wout[2] + gaf[3] * Wout[3] + e1 * Wout[4];
    float bad  = baf[0] * Wout[0] + baf[1] * Wout[1] + baf[2] * Wout[2] + baf[3] * Wout[3] + e2 * Wout[4];
    float loss = fmaxf(0.0f, 1.0f + bad - good);
    out[0] = loss; out[1] = good; out[2] = bad;
  }
}

extern "C" void kernel_launch(void* const* d_in, const int* in_sizes, int n_in,
                              void* d_out, int out_size, void* d_ws, size_t ws_size,
                              hipStream_t stream) {
  const float* d1   = (const float*)d_in[0];
  const float* d2   = (const float*)d_in[1];
  const float* qe   = (const float*)d_in[2];
  const float* qidf = (const float*)d_in[3];
  const float* gaf  = (const float*)d_in[4];
  const float* baf  = (const float*)d_in[5];
  const float* Wc   = (const float*)d_in[6];
  const float* bc   = (const float*)d_in[7];
  const float* Wqw  = (const float*)d_in[8];
  const float* Wq1  = (const float*)d_in[9];
  const float* Wq2  = (const float*)d_in[10];
  const float* Wout = (const float*)d_in[11];
  int D = in_sizes[0] / EMB;
  int Q = in_sizes[2] / EMB;

  unsigned short* us = (unsigned short*)d_ws;
  unsigned short* cmb = us; us += (size_t)D * 128;
  unsigned short* qrA = us; us += (size_t)Q * 32;
  unsigned short* qcA = us; us += (size_t)Q * 32;
  float* fp = (float*)us;
  float* logits    = fp; fp += Q;
  float* partials  = fp; fp += (size_t)Q * NS * 20;
  float* blockSums = fp; fp += (Q / 4) * 2;

  int grid = (Q >> 6) + 2 * (D >> 6);
  prep_all_kernel<<<grid, 256, 0, stream>>>(qe, d1, d2, Q, D, Wc, bc, qidf, Wqw,
                                            qrA, qcA, cmb, logits);
  main_kernel<<<(Q / 128) * NS, 256, 0, stream>>>(qrA, qcA, (const unsigned*)cmb,
                                                  partials, Q, D);
  pool_kernel<<<Q / 4, 256, 0, stream>>>(logits, partials, Wq1, Wq2, blockSums, Q);
  final_kernel<<<1, 64, 0, stream>>>(blockSums, Q / 4, gaf, baf, Wout, (float*)d_out, Q);
}